// Round 2
// baseline (3508.179 us; speedup 1.0000x reference)
//
#include <hip/hip_runtime.h>

typedef __bf16 bf16_t;
typedef __bf16 bf16x8 __attribute__((ext_vector_type(8)));
typedef __bf16 bf16x4 __attribute__((ext_vector_type(4)));
typedef float  f32x4  __attribute__((ext_vector_type(4)));

#define AS1 __attribute__((address_space(1)))
#define AS3 __attribute__((address_space(3)))

// ---------------------------------------------------------------------------
// Unified NT GEMM:  D[m][n] = sum_k A[m][k] * Bt[n][k]   (both K-contiguous)
// OUTMN=0: store C[n][m] (activation layout), OUTMN=1: store C[m][n].
// CONV: K = 3*CIN, Bt row n is x[n + tap - 1][c] with zero-page at batch edges.
// ---------------------------------------------------------------------------
template<int BM, int BN, int OUTMN, int CONV, int BIAS, int RELU, int MASK>
__global__ __launch_bounds__(256)
void gemm_nt(const bf16_t* __restrict__ A, const bf16_t* __restrict__ B,
             bf16_t* __restrict__ C, const float* __restrict__ bias,
             const float* __restrict__ mask, const bf16_t* __restrict__ zpage,
             int K, int lda, int ldb, int ldc, int CIN,
             long sAb, long sAh, long sBb, long sBh, long sCb, long sCh)
{
    constexpr int BK = 32;
    __shared__ bf16_t As[BM * BK];
    __shared__ bf16_t Bs[BN * BK];
    const int z = blockIdx.z;
    A += (long)(z >> 3) * sAb + (long)(z & 7) * sAh;
    B += (long)(z >> 3) * sBb + (long)(z & 7) * sBh;
    C += (long)(z >> 3) * sCb + (long)(z & 7) * sCh;
    const int m0 = blockIdx.y * BM;
    const int n0 = blockIdx.x * BN;
    const int tid = threadIdx.x;
    const int wid = tid >> 6, lane = tid & 63;
    constexpr int WM = BM / 2, WN = BN / 2;
    constexpr int FM = WM / 16, FN = WN / 16;
    const int wm = wid >> 1, wn = wid & 1;

    f32x4 acc[FM][FN] = {};

    constexpr int ACH = BM / 64;   // A chunks (16 rows = 1KB) per wave
    constexpr int BCH = BN / 64;
    const int rquad = lane >> 2;          // row within 16-row chunk
    const int koff  = (lane & 3) * 8;     // element offset along K

    int tap = 0, cc0 = 0;
    for (int k0 = 0; k0 < K; k0 += BK) {
        #pragma unroll
        for (int q = 0; q < ACH; ++q) {
            int ch  = wid * ACH + q;
            int row = ch * 16 + rquad;
            const bf16_t* src = A + (long)(m0 + row) * lda + (k0 + koff);
            __builtin_amdgcn_global_load_lds((const AS1 void*)src,
                                             (AS3 void*)(As + ch * 512), 16, 0, 0);
        }
        #pragma unroll
        for (int q = 0; q < BCH; ++q) {
            int ch  = wid * BCH + q;
            int row = ch * 16 + rquad;
            const bf16_t* src;
            if constexpr (CONV) {
                int tl = (n0 & 1023) + row + tap - 1;
                src = ((unsigned)tl < 1024u)
                    ? B + (long)(n0 + row + tap - 1) * ldb + (cc0 + koff)
                    : zpage + koff;
            } else {
                src = B + (long)(n0 + row) * ldb + (k0 + koff);
            }
            __builtin_amdgcn_global_load_lds((const AS1 void*)src,
                                             (AS3 void*)(Bs + ch * 512), 16, 0, 0);
        }
        if constexpr (CONV) { cc0 += BK; if (cc0 == CIN) { cc0 = 0; ++tap; } }
        __syncthreads();

        const bf16_t* Ab = As + (wm * WM + (lane & 15)) * BK + ((lane >> 4) * 8);
        const bf16_t* Bb = Bs + (wn * WN + (lane & 15)) * BK + ((lane >> 4) * 8);
        bf16x8 af[FM], bv[FN];
        #pragma unroll
        for (int i = 0; i < FM; ++i) af[i] = *(const bf16x8*)(Ab + i * 16 * BK);
        #pragma unroll
        for (int j = 0; j < FN; ++j) bv[j] = *(const bf16x8*)(Bb + j * 16 * BK);
        #pragma unroll
        for (int i = 0; i < FM; ++i)
            #pragma unroll
            for (int j = 0; j < FN; ++j)
                acc[i][j] = __builtin_amdgcn_mfma_f32_16x16x32_bf16(af[i], bv[j], acc[i][j], 0, 0, 0);
        __syncthreads();
    }

    const int mw = m0 + wm * WM, nw = n0 + wn * WN;
    #pragma unroll
    for (int i = 0; i < FM; ++i) {
        const int mb = mw + i * 16 + (lane >> 4) * 4;
        f32x4 bvv = {};
        if constexpr (BIAS) bvv = *(const f32x4*)(bias + mb);
        #pragma unroll
        for (int j = 0; j < FN; ++j) {
            const int nn = nw + j * 16 + (lane & 15);
            f32x4 v = acc[i][j];
            if constexpr (BIAS) v += bvv;
            if constexpr (RELU) {
                #pragma unroll
                for (int r = 0; r < 4; ++r) v[r] = fmaxf(v[r], 0.f);
            }
            if constexpr (MASK) v *= mask[nn];
            if constexpr (OUTMN) {
                #pragma unroll
                for (int r = 0; r < 4; ++r) C[(long)(mb + r) * ldc + nn] = (bf16_t)v[r];
            } else {
                bf16x4 o;
                #pragma unroll
                for (int r = 0; r < 4; ++r) o[r] = (bf16_t)v[r];
                *(bf16x4*)(C + (long)nn * ldc + mb) = o;
            }
        }
    }
}

// ---------------------------------------------------------------------------
// R[bh,t,j] = sum_d q_scaled[b*1024+t][h*64+d] * erk[j][d]   (wave per (bh,t))
// All 64 bh at once.
// ---------------------------------------------------------------------------
__global__ __launch_bounds__(256)
void rel_qk(const bf16_t* __restrict__ qk, const float* __restrict__ erk_l,
            float* __restrict__ R)
{
    int gw = blockIdx.x * 4 + (threadIdx.x >> 6);
    int z = gw >> 10, t = gw & 1023;
    int b = z >> 3, h = z & 7;
    int lane = threadIdx.x & 63;
    float qv = (float)qk[(long)(b * 1024 + t) * 1024 + h * 64 + lane];
    float r[9];
    #pragma unroll
    for (int j = 0; j < 9; ++j) r[j] = qv * erk_l[j * 64 + lane];
    #pragma unroll
    for (int o = 1; o < 64; o <<= 1)
        #pragma unroll
        for (int j = 0; j < 9; ++j) r[j] += __shfl_xor(r[j], o);
    if (lane == 0) {
        #pragma unroll
        for (int j = 0; j < 9; ++j) R[(long)gw * 9 + j] = r[j];
    }
}

// ---------------------------------------------------------------------------
// In-place softmax over rows of S (bf16), with banded rel add + mask.
// Operates on a 2-batch chunk: S is chunk base, R/mask are chunk-offset ptrs.
// ---------------------------------------------------------------------------
__global__ __launch_bounds__(256)
void softmax_band(bf16_t* __restrict__ S, const float* __restrict__ R,
                  const float* __restrict__ mask)
{
    int gw = blockIdx.x * 4 + (threadIdx.x >> 6);   // < 16384 (2 batches)
    int z = gw >> 10, t = gw & 1023;
    int b = z >> 3;                                  // local batch 0/1
    int lane = threadIdx.x & 63;
    bf16_t* row = S + (long)gw * 1024;
    const float* Rp = R + (long)gw * 9;
    int sbase = lane * 16;
    bf16x8 r0 = *(const bf16x8*)(row + sbase);
    bf16x8 r1 = *(const bf16x8*)(row + sbase + 8);
    float vals[16];
    #pragma unroll
    for (int e = 0; e < 8; ++e) { vals[e] = (float)r0[e]; vals[8 + e] = (float)r1[e]; }
    #pragma unroll
    for (int e = 0; e < 16; ++e) {
        int j = sbase + e - t + 4;
        if (j >= 0 && j < 9) vals[e] += Rp[j];
    }
    float mt = mask[b * 1024 + t];
    const float* ms = mask + b * 1024 + sbase;
    #pragma unroll
    for (int e = 0; e < 16; ++e)
        if (mt * ms[e] == 0.f) vals[e] = -1e4f;
    float mx = vals[0];
    #pragma unroll
    for (int e = 1; e < 16; ++e) mx = fmaxf(mx, vals[e]);
    #pragma unroll
    for (int o = 1; o < 64; o <<= 1) mx = fmaxf(mx, __shfl_xor(mx, o));
    float sm = 0.f;
    #pragma unroll
    for (int e = 0; e < 16; ++e) { vals[e] = __expf(vals[e] - mx); sm += vals[e]; }
    #pragma unroll
    for (int o = 1; o < 64; o <<= 1) sm += __shfl_xor(sm, o);
    float inv = 1.f / sm;
    bf16x8 w0, w1;
    #pragma unroll
    for (int e = 0; e < 8; ++e) { w0[e] = (bf16_t)(vals[e] * inv); w1[e] = (bf16_t)(vals[8 + e] * inv); }
    *(bf16x8*)(row + sbase) = w0;
    *(bf16x8*)(row + sbase + 8) = w1;
}

// ---------------------------------------------------------------------------
// attn_out[(b*1024+t)*512 + h*64+d] += sum_j P[t][t+j-4] * erv[j][d]  (chunk)
// ---------------------------------------------------------------------------
__global__ __launch_bounds__(256)
void rel_pv_add(const bf16_t* __restrict__ P, const float* __restrict__ erv_l,
                bf16_t* __restrict__ attn_out)
{
    int gw = blockIdx.x * 4 + (threadIdx.x >> 6);   // < 16384 (2 batches)
    int z = gw >> 10, t = gw & 1023, b = z >> 3, h = z & 7;
    int lane = threadIdx.x & 63;
    const bf16_t* prow = P + (long)gw * 1024;
    float a = 0.f;
    #pragma unroll
    for (int j = 0; j < 9; ++j) {
        int s = t + j - 4;
        if ((unsigned)s < 1024u) a += (float)prow[s] * erv_l[j * 64 + lane];
    }
    long idx = (long)(b * 1024 + t) * 512 + h * 64 + lane;
    attn_out[idx] = (bf16_t)((float)attn_out[idx] + a);
}

// ---------------------------------------------------------------------------
// Residual + LayerNorm over C=512 (wave per row n). Writes fp32 xres and bf16
// xbf (optionally masked).
// ---------------------------------------------------------------------------
template<int MASKOUT>
__global__ __launch_bounds__(256)
void ln_residual(float* __restrict__ xres, const bf16_t* __restrict__ y,
                 bf16_t* __restrict__ xbf, const float* __restrict__ g,
                 const float* __restrict__ bvec, const float* __restrict__ mask)
{
    int gw = blockIdx.x * 4 + (threadIdx.x >> 6);
    int lane = threadIdx.x & 63;
    long base = (long)gw * 512 + lane * 8;
    f32x4 x0 = *(const f32x4*)(xres + base);
    f32x4 x1 = *(const f32x4*)(xres + base + 4);
    bf16x8 yv = *(const bf16x8*)(y + base);
    float s[8];
    #pragma unroll
    for (int e = 0; e < 4; ++e) { s[e] = x0[e] + (float)yv[e]; s[4 + e] = x1[e] + (float)yv[4 + e]; }
    float sum = 0.f, sq = 0.f;
    #pragma unroll
    for (int e = 0; e < 8; ++e) { sum += s[e]; sq += s[e] * s[e]; }
    #pragma unroll
    for (int o = 1; o < 64; o <<= 1) { sum += __shfl_xor(sum, o); sq += __shfl_xor(sq, o); }
    float mean = sum * (1.f / 512.f);
    float var  = sq * (1.f / 512.f) - mean * mean;
    float rstd = rsqrtf(var + 1e-5f);
    f32x4 g0 = *(const f32x4*)(g + lane * 8);
    f32x4 g1 = *(const f32x4*)(g + lane * 8 + 4);
    f32x4 b0 = *(const f32x4*)(bvec + lane * 8);
    f32x4 b1 = *(const f32x4*)(bvec + lane * 8 + 4);
    float mk = MASKOUT ? mask[gw] : 1.f;
    f32x4 o0, o1; bf16x8 ob;
    #pragma unroll
    for (int e = 0; e < 4; ++e) {
        float v0 = (s[e] - mean) * rstd * g0[e] + b0[e];
        float v1 = (s[4 + e] - mean) * rstd * g1[e] + b1[e];
        o0[e] = v0; o1[e] = v1;
        ob[e] = (bf16_t)(v0 * mk); ob[4 + e] = (bf16_t)(v1 * mk);
    }
    *(f32x4*)(xres + base) = o0;
    *(f32x4*)(xres + base + 4) = o1;
    *(bf16x8*)(xbf + base) = ob;
}

// ---------------------------------------------------------------------------
// Transposes: x[B,C,T] <-> act[B*T, C]
// ---------------------------------------------------------------------------
__global__ __launch_bounds__(256)
void transpose_in_k(const float* __restrict__ x, const float* __restrict__ mask,
                    float* __restrict__ xres, bf16_t* __restrict__ xbf)
{
    __shared__ float tile[32][33];
    int b = blockIdx.z, c0 = blockIdx.y * 32, t0 = blockIdx.x * 32;
    int tx = threadIdx.x & 31, ty = threadIdx.x >> 5;
    #pragma unroll
    for (int r = 0; r < 4; ++r) {
        int cl = ty + r * 8;
        tile[cl][tx] = x[((long)b * 512 + c0 + cl) * 1024 + t0 + tx];
    }
    __syncthreads();
    #pragma unroll
    for (int r = 0; r < 4; ++r) {
        int tl = ty + r * 8;
        int n = b * 1024 + t0 + tl;
        float v = tile[tx][tl] * mask[n];
        xres[(long)n * 512 + c0 + tx] = v;
        xbf[(long)n * 512 + c0 + tx] = (bf16_t)v;
    }
}

__global__ __launch_bounds__(256)
void transpose_out_k(const float* __restrict__ xres, const float* __restrict__ mask,
                     float* __restrict__ out)
{
    __shared__ float tile[32][33];
    int b = blockIdx.z, c0 = blockIdx.y * 32, t0 = blockIdx.x * 32;
    int tx = threadIdx.x & 31, ty = threadIdx.x >> 5;
    #pragma unroll
    for (int r = 0; r < 4; ++r) {
        int tl = ty + r * 8;
        int n = b * 1024 + t0 + tl;
        tile[tl][tx] = xres[(long)n * 512 + c0 + tx] * mask[n];
    }
    __syncthreads();
    #pragma unroll
    for (int r = 0; r < 4; ++r) {
        int cl = ty + r * 8;
        out[((long)b * 512 + c0 + cl) * 1024 + t0 + tx] = tile[tx][cl];
    }
}

// ---------------------------------------------------------------------------
// Per-layer weight packing (fp32 -> bf16, q-scale fold, conv k-major repack)
// w points at the LAYER's weights.
// ---------------------------------------------------------------------------
__global__ __launch_bounds__(256)
void pack_attn_w(const float* __restrict__ w, bf16_t* __restrict__ Wqk,
                 bf16_t* __restrict__ Wv, bf16_t* __restrict__ Wo)
{
    int idx = blockIdx.x * 256 + threadIdx.x;      // < 4*512*512
    if (idx >= 4 * 512 * 512) return;
    int c = idx & 511;
    int o = (idx >> 9) & 511;
    int which = idx >> 18;
    float v = w[idx];
    if (which == 0) v *= 0.125f;
    if (which <= 1)      Wqk[(which * 512 + o) * 512 + c] = (bf16_t)v;
    else if (which == 2) Wv[o * 512 + c] = (bf16_t)v;
    else                 Wo[o * 512 + c] = (bf16_t)v;
}

__global__ __launch_bounds__(256)
void pack_attn_b(const float* __restrict__ bsrc, float* __restrict__ bqk)
{
    int idx = blockIdx.x * 256 + threadIdx.x;
    if (idx >= 6 * 2 * 512) return;     // only q,k need packing (q scaled)
    int c = idx & 511, which = (idx >> 9) & 1, i = idx >> 10;
    float v = bsrc[(i * 4 + which) * 512 + c];
    if (which == 0) v *= 0.125f;
    bqk[i * 1024 + which * 512 + c] = v;
}

__global__ __launch_bounds__(256)
void pack_w1k(const float* __restrict__ w, bf16_t* __restrict__ Wp)
{
    int idx = blockIdx.x * 256 + threadIdx.x;      // < 2048*1536
    if (idx >= 2048 * 1536) return;
    int c = idx & 511;
    int k = (idx >> 9) % 3;
    int f = idx / 1536;
    Wp[idx] = (bf16_t)w[(f * 512 + c) * 3 + k];    // w1[f][c][k] -> Wp[f][k][c]
}

__global__ __launch_bounds__(256)
void pack_w2k(const float* __restrict__ w, bf16_t* __restrict__ Wp)
{
    int idx = blockIdx.x * 256 + threadIdx.x;      // < 512*6144
    if (idx >= 512 * 6144) return;
    int f = idx & 2047;
    int k = (idx >> 11) % 3;
    int ci = idx / 6144;
    Wp[idx] = (bf16_t)w[ci * 6144 + f * 3 + k];    // w2[c][f][k] -> Wp[c][k][f]
}

// ---------------------------------------------------------------------------
extern "C" void kernel_launch(void* const* d_in, const int* in_sizes, int n_in,
                              void* d_out, int out_size, void* d_ws, size_t ws_size,
                              hipStream_t stream)
{
    const float* x      = (const float*)d_in[0];
    const float* xmask  = (const float*)d_in[1];
    const float* attn_w = (const float*)d_in[2];
    const float* attn_b = (const float*)d_in[3];
    const float* erk    = (const float*)d_in[4];
    const float* erv    = (const float*)d_in[5];
    const float* ln1g   = (const float*)d_in[6];
    const float* ln1b   = (const float*)d_in[7];
    const float* w1     = (const float*)d_in[8];
    const float* b1in   = (const float*)d_in[9];
    const float* w2     = (const float*)d_in[10];
    const float* b2in   = (const float*)d_in[11];
    const float* ln2g   = (const float*)d_in[12];
    const float* ln2b   = (const float*)d_in[13];
    float* out = (float*)d_out;

    char* p = (char*)d_ws;
    auto alloc = [&](size_t bytes) {
        char* r = p;
        p += (bytes + 255) & ~(size_t)255;
        return r;
    };
    // total ws usage ~118 MB (was 325 MB in round 1 -> presumed page fault)
    bf16_t* zpage = (bf16_t*)alloc(1024);
    bf16_t* Wqk_l = (bf16_t*)alloc(1024l * 512 * 2);
    bf16_t* Wv_l  = (bf16_t*)alloc(512l * 512 * 2);
    bf16_t* Wo_l  = (bf16_t*)alloc(512l * 512 * 2);
    bf16_t* W1p_l = (bf16_t*)alloc(2048l * 1536 * 2);
    bf16_t* W2p_l = (bf16_t*)alloc(512l * 6144 * 2);
    float*  bqk   = (float*)alloc(6l * 1024 * 4);
    float*  xres  = (float*)alloc(8192l * 512 * 4);
    bf16_t* xbf   = (bf16_t*)alloc(8192l * 512 * 2);
    bf16_t* big   = (bf16_t*)alloc(8192l * 2048 * 2);   // qk|vt|attn_out, aliased by hbuf
    bf16_t* ybuf  = (bf16_t*)alloc(8192l * 512 * 2);
    bf16_t* S     = (bf16_t*)alloc(16l * 1024 * 1024 * 2);  // 2-batch chunk
    float*  R     = (float*)alloc(64l * 1024 * 9 * 4);
    (void)in_sizes; (void)n_in; (void)out_size; (void)ws_size;

    bf16_t* qk       = big;                    // [8192][1024]
    bf16_t* vt       = big + 8192l * 1024;     // [512][8192]
    bf16_t* attn_out = vt + 512l * 8192;       // [8192][512]
    bf16_t* hbuf     = big;                    // [8192][2048], aliases all three

    hipMemsetAsync(zpage, 0, 1024, stream);
    pack_attn_b<<<24, 256, 0, stream>>>(attn_b, bqk);
    transpose_in_k<<<dim3(32, 16, 8), 256, 0, stream>>>(x, xmask, xres, xbf);

    for (int i = 0; i < 6; ++i) {
        pack_attn_w<<<4096, 256, 0, stream>>>(attn_w + (long)i * 4 * 512 * 512,
                                              Wqk_l, Wv_l, Wo_l);
        pack_w1k<<<12288, 256, 0, stream>>>(w1 + (long)i * 2048 * 512 * 3, W1p_l);
        pack_w2k<<<12288, 256, 0, stream>>>(w2 + (long)i * 512 * 2048 * 3, W2p_l);

        // QK projection (q pre-scaled): [1024,512] x [8192,512]^T -> qk[n][m]
        gemm_nt<128, 128, 0, 0, 1, 0, 0><<<dim3(64, 8, 1), 256, 0, stream>>>(
            Wqk_l, xbf, qk, bqk + i * 1024, nullptr, zpage,
            512, 512, 512, 1024, 0, 0, 0, 0, 0, 0, 0);
        // V projection -> channel-major vt[c][n]
        gemm_nt<128, 128, 1, 0, 1, 0, 0><<<dim3(64, 4, 1), 256, 0, stream>>>(
            Wv_l, xbf, vt, attn_b + (i * 4 + 2) * 512, nullptr, zpage,
            512, 512, 512, 8192, 0, 0, 0, 0, 0, 0, 0);
        // R table for banded rel-k logits (all 64 bh)
        rel_qk<<<16384, 256, 0, stream>>>(qk, erk + i * 576, R);

        for (int bc = 0; bc < 4; ++bc) {
            int b0 = bc * 2;
            // scores S[t][s] per (b,h), 2 batches
            gemm_nt<128, 128, 1, 0, 0, 0, 0><<<dim3(8, 8, 16), 256, 0, stream>>>(
                qk + (long)b0 * 1048576, qk + 512 + (long)b0 * 1048576, S,
                nullptr, nullptr, zpage,
                64, 1024, 1024, 1024, 0,
                1048576, 64, 1048576, 64, 8l * 1048576, 1048576);
            // band add + mask + softmax (in place -> P)
            softmax_band<<<4096, 256, 0, stream>>>(S, R + (long)b0 * 73728,
                                                   xmask + b0 * 1024);
            // out[t][d] = P x V
            gemm_nt<128, 64, 1, 0, 0, 0, 0><<<dim3(1, 8, 16), 256, 0, stream>>>(
                S, vt + (long)b0 * 1024, attn_out + (long)b0 * 524288,
                nullptr, nullptr, zpage,
                1024, 1024, 8192, 512, 0,
                8l * 1048576, 1048576, 1024, 64l * 8192, 524288, 64);
            // banded rel-v accumulation
            rel_pv_add<<<4096, 256, 0, stream>>>(S, erv + i * 576,
                                                 attn_out + (long)b0 * 524288);
        }

        // O projection
        gemm_nt<128, 128, 0, 0, 1, 0, 0><<<dim3(64, 4, 1), 256, 0, stream>>>(
            Wo_l, attn_out, ybuf, attn_b + (i * 4 + 3) * 512, nullptr, zpage,
            512, 512, 512, 512, 0, 0, 0, 0, 0, 0, 0);
        // LN1 (xbf masked for conv1 input)
        ln_residual<1><<<2048, 256, 0, stream>>>(xres, ybuf, xbf,
                                                 ln1g + i * 512, ln1b + i * 512, xmask);
        // conv1 (K=3*512) + bias + relu + mask   (hbuf aliases attn region - dead)
        gemm_nt<128, 128, 0, 1, 1, 1, 1><<<dim3(64, 16, 1), 256, 0, stream>>>(
            W1p_l, xbf, hbuf, b1in + i * 2048, xmask, zpage,
            1536, 1536, 512, 2048, 512, 0, 0, 0, 0, 0, 0);
        // conv2 (K=3*2048) + bias + mask
        gemm_nt<128, 128, 0, 1, 1, 0, 1><<<dim3(64, 4, 1), 256, 0, stream>>>(
            W2p_l, hbuf, ybuf, b2in + i * 512, xmask, zpage,
            6144, 6144, 2048, 512, 2048, 0, 0, 0, 0, 0, 0);
        // LN2 (xbf unmasked -> next layer's attention input)
        ln_residual<0><<<2048, 256, 0, stream>>>(xres, ybuf, xbf,
                                                 ln2g + i * 512, ln2b + i * 512, xmask);
    }

    transpose_out_k<<<dim3(32, 16, 8), 256, 0, stream>>>(xres, xmask, out);
}